// Round 5
// baseline (13638.666 us; speedup 1.0000x reference)
//
#include <hip/hip_runtime.h>
#include <stdint.h>

typedef uint16_t u16;
typedef __attribute__((ext_vector_type(8))) short bf16x8;   // 8 bf16 in 4 VGPRs
typedef __attribute__((ext_vector_type(4))) float f32x4;
typedef __attribute__((ext_vector_type(4))) unsigned u32x4;

#define DEVI __device__ __forceinline__

DEVI u16 f2b(float f) {                       // f32 -> bf16 RNE
  uint32_t u = __float_as_uint(f);
  uint32_t r = (u + 0x7fffu + ((u >> 16) & 1u)) >> 16;
  return (u16)r;
}
DEVI float b2f(u16 h) { return __uint_as_float(((uint32_t)h) << 16); }

typedef const __attribute__((address_space(1))) uint32_t* gptr_t;
typedef __attribute__((address_space(3))) uint32_t* lptr_t;
DEVI void gload_lds16(const void* g, void* l) {
  __builtin_amdgcn_global_load_lds((gptr_t)g, (lptr_t)l, 16, 0, 0);
}

// L2-bypass (coherent-at-L3) accessors for cross-XCD h exchange.
DEVI bf16x8 ld_cc16(const u16* p) {
  bf16x8 r;
  asm volatile("global_load_dwordx4 %0, %1, off sc0 sc1" : "=v"(r) : "v"(p));
  return r;   // caller must s_waitcnt vmcnt(0) + sched_barrier before use
}
DEVI void st_cc2(u16* p, u16 v) {
  uint32_t d = v;
  asm volatile("global_store_short %0, %1, off sc0 sc1" :: "v"(p), "v"(d) : "memory");
}

// ---------------------------------------------------------------- converts
__global__ void cvt_f32_bf16(const float* __restrict__ in, u16* __restrict__ out, long n) {
  long i = ((long)blockIdx.x * blockDim.x + threadIdx.x) * 4;
  long stride = (long)gridDim.x * blockDim.x * 4;
  for (; i < n; i += stride) {
    float4 v = *(const float4*)(in + i);
    ushort4 o;
    o.x = f2b(v.x); o.y = f2b(v.y); o.z = f2b(v.z); o.w = f2b(v.w);
    *(ushort4*)(out + i) = o;
  }
}

// ---------------------------------------------------------------- GEMM
// C[m,n] = sum_k A[m,k]*W[n,k] + bias[n]; M=32768, N=6144; 128x128 tile, BK=64.
__global__ __launch_bounds__(256) void gemm_bt_bias(
    const u16* __restrict__ A, const u16* __restrict__ W,
    const float* __restrict__ bias, u16* __restrict__ C, int K) {
  constexpr int NLD = 6144;
  __shared__ u16 As[128 * 64];
  __shared__ u16 Bs[128 * 64];
  const int t = threadIdx.x;
  const int l = t & 63, w = t >> 6;
  const int lr = l & 15, lk = l >> 4;
  const long bm = (long)blockIdx.y * 128;
  const long bn = (long)blockIdx.x * 128;
  const int wm = (w >> 1) * 64, wn = (w & 1) * 64;

  f32x4 acc[4][4] = {};

  for (int k0 = 0; k0 < K; k0 += 64) {
    __syncthreads();
    #pragma unroll
    for (int i = 0; i < 4; ++i) {
      int slot = i * 256 + t;
      int row = slot >> 3, s = slot & 7;
      int c8 = (s ^ (row & 7)) * 8;
      char* la = (char*)As + (size_t)(i * 256 + w * 64) * 16;
      char* lb = (char*)Bs + (size_t)(i * 256 + w * 64) * 16;
      gload_lds16(A + (bm + row) * K + k0 + c8, la);
      gload_lds16(W + (bn + row) * K + k0 + c8, lb);
    }
    asm volatile("s_waitcnt vmcnt(0)" ::: "memory");
    __syncthreads();
    #pragma unroll
    for (int kk = 0; kk < 2; ++kk) {
      bf16x8 af[4], bfr[4];
      #pragma unroll
      for (int mi = 0; mi < 4; ++mi) {
        int row = wm + mi * 16 + lr;
        int sl = (kk * 4 + lk) ^ (row & 7);
        af[mi] = *(const bf16x8*)((const char*)As + row * 128 + sl * 16);
      }
      #pragma unroll
      for (int ni = 0; ni < 4; ++ni) {
        int row = wn + ni * 16 + lr;
        int sl = (kk * 4 + lk) ^ (row & 7);
        bfr[ni] = *(const bf16x8*)((const char*)Bs + row * 128 + sl * 16);
      }
      #pragma unroll
      for (int mi = 0; mi < 4; ++mi)
        #pragma unroll
        for (int ni = 0; ni < 4; ++ni)
          acc[mi][ni] = __builtin_amdgcn_mfma_f32_16x16x32_bf16(af[mi], bfr[ni], acc[mi][ni], 0, 0, 0);
    }
  }

  float bv[4];
  #pragma unroll
  for (int ni = 0; ni < 4; ++ni) bv[ni] = bias[bn + wn + ni * 16 + lr];
  #pragma unroll
  for (int mi = 0; mi < 4; ++mi)
    #pragma unroll
    for (int ni = 0; ni < 4; ++ni) {
      long col = bn + wn + ni * 16 + lr;
      #pragma unroll
      for (int j = 0; j < 4; ++j) {
        long row = bm + wm + mi * 16 + lk * 4 + j;
        C[row * NLD + col] = f2b(acc[mi][ni][j] + bv[ni]);
      }
    }
}

// ---------------------------------------------------------------- slot barrier
// Store-only (no RMW): WG writes its domain slot (sc0sc1 -> L3), wave 0 polls
// all 64 slots via 16-lane dwordx4. Monotone targets, no resets, no fences.
DEVI void slot_barrier(unsigned* slots, int jg, unsigned tgt, int l) {
  if (l == 0)
    asm volatile("global_store_dword %0, %1, off sc0 sc1" :: "v"(slots + jg), "v"(tgt) : "memory");
  const unsigned* pp = slots + (l & 15) * 4;
  for (;;) {
    u32x4 v;
    asm volatile("global_load_dwordx4 %0, %1, off sc0 sc1" : "=v"(v) : "v"(pp));
    asm volatile("s_waitcnt vmcnt(0)" ::: "memory");
    int ok = (l < 16) ? (v.x >= tgt && v.y >= tgt && v.z >= tgt && v.w >= tgt) : 1;
    if (__all(ok)) break;
    __builtin_amdgcn_s_sleep(2);
  }
}

// ---------------------------------------------------------------- persistent GRU layer
// grid = 256 WGs x 512 thr (8 waves), 1 WG/CU. WG = (dir, jg, rp). Wave w2:
// kh=w2&3 (K-quarter), rt2=w2>>2 (16-row group). Weights parked in 96 AGPRs
// ("+a" launder) and consumed by inline-asm MFMA with "a" B-operand -- zero
// per-step weight traffic by construction. f32 master h in finish-lane regs;
// bf16 h published via sc0/sc1 (L3-coherent), read via sc0/sc1.
__global__ __launch_bounds__(512, 2) void gru_layer(
    u16* __restrict__ hbA, u16* __restrict__ hbB,
    const u16* __restrict__ Whh,   // [2,3072,1024] bf16 (this layer)
    const float* __restrict__ bhh, // [2,3072] f32
    const u16* __restrict__ gx,    // [32768,6144] bf16
    u16* __restrict__ y_b, float* __restrict__ y_f,   // one non-null
    const float* __restrict__ h0l, // [2,64,1024] f32 (this layer)
    unsigned* bar) {
  __shared__ float lds[8 * 64 * 13];

  const int bid = blockIdx.x;
  const int dir = bid >> 7;
  const int v = bid & 127;
  const int jg = v >> 1, rp = v & 1;
  const int tid = threadIdx.x;
  const int w2 = tid >> 6, l = tid & 63;
  const int lr = l & 15, lk = l >> 4;
  const int kh = w2 & 3, rt2 = w2 >> 2;
  const int rowbase = rp * 32 + rt2 * 16;

  unsigned* slots = bar + (size_t)(dir * 2 + rp) * 256;   // 64 u32 per domain

  // ---- park weights in AGPRs (96 AGPRs; nothing else uses the AGPR file)
  const u16* wb = Whh + ((size_t)dir * 3072 + jg * 16 + lr) * 1024 + kh * 256 + lk * 8;
  bf16x8 wr[8], wz[8], wn[8];
  #pragma unroll
  for (int kk = 0; kk < 8; ++kk) {
    wr[kk] = *(const bf16x8*)(wb + kk * 32);
    wz[kk] = *(const bf16x8*)(wb + 1024 * 1024 + kk * 32);
    wn[kk] = *(const bf16x8*)(wb + 2048 * 1024 + kk * 32);
  }
  #pragma unroll
  for (int kk = 0; kk < 8; ++kk)
    asm volatile("" : "+a"(wr[kk]), "+a"(wz[kk]), "+a"(wn[kk]));

  // ---- finish-lane constants + h-state init
  const int rl = tid >> 4, cl = tid & 15;     // rl in [0,32), cl in [0,16)
  const int fcol = jg * 16 + cl;
  const int frow = rp * 32 + rl;
  const float bhr = bhh[dir * 3072 + fcol];
  const float bhz = bhh[dir * 3072 + 1024 + fcol];
  const float bhn = bhh[dir * 3072 + 2048 + fcol];
  const size_t hoff = (size_t)(dir * 64 + frow) * 1024 + fcol;
  float hp = h0l[hoff];
  st_cc2(hbA + hoff, f2b(hp));                // visible at L3 to all XCDs

  const int tt0 = dir ? 511 : 0;
  long gxp = (long)(tt0 * 64 + frow) * 6144 + (long)dir * 3072 + fcol;
  const long gxstep = dir ? -(64 * 6144) : (64 * 6144);
  long yp = (long)(tt0 * 64 + frow) * 2048 + (long)dir * 1024 + fcol;
  const long ystep = dir ? -(64 * 2048) : (64 * 2048);

  const u16* apA = hbA + (size_t)(dir * 64 + rowbase + lr) * 1024 + kh * 256 + lk * 8;
  const u16* apB = hbB + (size_t)(dir * 64 + rowbase + lr) * 1024 + kh * 256 + lk * 8;

  const int rt2f = rl >> 4, r16 = rl & 15, jj = r16 & 3;
  const int lane2 = (r16 >> 2) * 16 + cl;

  asm volatile("s_waitcnt vmcnt(0)" ::: "memory");   // h0 publish drained to L3
  __syncthreads();
  if (w2 == 0) slot_barrier(slots, jg, 1u, l);
  __syncthreads();

  for (int t = 0; t < 512; ++t) {
    const u16* ap = (t & 1) ? apB : apA;
    u16* hb_out = (t & 1) ? hbA : hbB;

    // ---- co-issue h loads (sc0sc1) and gx loads (plain); one wait for all
    bf16x8 av[8];
    #pragma unroll
    for (int kk = 0; kk < 8; ++kk) av[kk] = ld_cc16(ap + kk * 32);
    unsigned gr = gx[gxp], gz = gx[gxp + 1024], gn = gx[gxp + 2048];
    asm volatile("" :: "v"(gr), "v"(gz), "v"(gn));   // force early materialization
    asm volatile("s_waitcnt vmcnt(0)" ::: "memory");
    __builtin_amdgcn_sched_barrier(0);

    // ---- 24 MFMAs, B-operand straight from AGPRs
    f32x4 aR = {0.f, 0.f, 0.f, 0.f}, aZ = {0.f, 0.f, 0.f, 0.f}, aN = {0.f, 0.f, 0.f, 0.f};
    asm volatile("s_nop 1");                          // VALU acc-init -> MFMA SrcC guard
    #pragma unroll
    for (int kk = 0; kk < 8; ++kk) {
      asm("v_mfma_f32_16x16x32_bf16 %0, %1, %2, %0" : "+v"(aR) : "v"(av[kk]), "a"(wr[kk]));
      asm("v_mfma_f32_16x16x32_bf16 %0, %1, %2, %0" : "+v"(aZ) : "v"(av[kk]), "a"(wz[kk]));
      asm("v_mfma_f32_16x16x32_bf16 %0, %1, %2, %0" : "+v"(aN) : "v"(av[kk]), "a"(wn[kk]));
    }
    asm volatile("s_nop 7\n\ts_nop 7");               // MFMA D -> VALU/DS read guard

    float* myl = lds + (size_t)(w2 * 64 + l) * 13;
    #pragma unroll
    for (int j = 0; j < 4; ++j) { myl[j] = aR[j]; myl[4 + j] = aZ[j]; myl[8 + j] = aN[j]; }
    __syncthreads();

    // ---- finish: combine 4 K-partials, gate math, publish
    float ghr = 0.f, ghz = 0.f, ghn = 0.f;
    #pragma unroll
    for (int k2 = 0; k2 < 4; ++k2) {
      const float* pl = lds + (size_t)((rt2f * 4 + k2) * 64 + lane2) * 13;
      ghr += pl[jj]; ghz += pl[4 + jj]; ghn += pl[8 + jj];
    }
    float rg = 1.f / (1.f + __expf(-(b2f((u16)gr) + ghr + bhr)));
    float zg = 1.f / (1.f + __expf(-(b2f((u16)gz) + ghz + bhz)));
    float ng = tanhf(b2f((u16)gn) + rg * (ghn + bhn));
    hp = (1.f - zg) * ng + zg * hp;
    st_cc2(hb_out + hoff, f2b(hp));                   // sc0sc1 -> L3
    if (y_b) y_b[yp] = f2b(hp);                       // plain cached store
    else     y_f[yp] = hp;
    gxp += gxstep; yp += ystep;

    asm volatile("s_waitcnt vmcnt(0)" ::: "memory");  // h publish + y store drained
    __syncthreads();
    if (w2 == 0) slot_barrier(slots, jg, (unsigned)(t + 2), l);
    __syncthreads();
  }
}

// ---------------------------------------------------------------- launch
extern "C" void kernel_launch(void* const* d_in, const int* in_sizes, int n_in,
                              void* d_out, int out_size, void* d_ws, size_t ws_size,
                              hipStream_t stream) {
  (void)in_sizes; (void)n_in; (void)out_size; (void)ws_size;
  const float* x     = (const float*)d_in[0];   // [512,64,1024]
  const float* h0    = (const float*)d_in[1];   // [6,64,1024]
  const float* w_ih0 = (const float*)d_in[2];   // [2,3072,1024]
  const float* w_ih  = (const float*)d_in[3];   // [2,2,3072,2048]
  const float* w_hh  = (const float*)d_in[4];   // [3,2,3072,1024]
  const float* b_ih  = (const float*)d_in[5];   // [3,2,3072]
  const float* b_hh  = (const float*)d_in[6];   // [3,2,3072]
  float* out = (float*)d_out;                   // [512,64,2048]

  char* p = (char*)d_ws;
  u16* wA    = (u16*)p; p += (size_t)32768 * 2048 * 2;       // layer input bf16
  u16* wGx   = (u16*)p; p += (size_t)32768 * 6144 * 2;       // gate preacts bf16
  u16* wWih0 = (u16*)p; p += (size_t)6144 * 1024 * 2;
  u16* wWih  = (u16*)p; p += (size_t)2 * 6144 * 2048 * 2;
  u16* wWhh  = (u16*)p; p += (size_t)6 * 3072 * 1024 * 2;
  u16* wHb0  = (u16*)p; p += (size_t)2 * 64 * 1024 * 2;
  u16* wHb1  = (u16*)p; p += (size_t)2 * 64 * 1024 * 2;
  unsigned* wBar = (unsigned*)p; p += 4096 * 4;

  cvt_f32_bf16<<<2048, 256, 0, stream>>>(x,     wA,    (long)33554432);
  cvt_f32_bf16<<<2048, 256, 0, stream>>>(w_ih0, wWih0, (long)6291456);
  cvt_f32_bf16<<<2048, 256, 0, stream>>>(w_ih,  wWih,  (long)25165824);
  cvt_f32_bf16<<<2048, 256, 0, stream>>>(w_hh,  wWhh,  (long)18874368);

  for (int layer = 0; layer < 3; ++layer) {
    int K = (layer == 0) ? 1024 : 2048;
    const u16* Wg = (layer == 0) ? wWih0 : (wWih + (size_t)(layer - 1) * 6144 * 2048);
    gemm_bt_bias<<<dim3(48, 256), 256, 0, stream>>>(wA, Wg, b_ih + (size_t)layer * 6144, wGx, K);

    hipMemsetAsync(wBar, 0, 4096 * 4, stream);

    const u16* Whh_l   = wWhh + (size_t)layer * 2 * 3072 * 1024;
    const float* bhh_l = b_hh + (size_t)layer * 6144;
    const float* h0_l  = h0 + (size_t)layer * 131072;
    u16*   yb = (layer < 2) ? wA : nullptr;
    float* yf = (layer < 2) ? nullptr : out;
    gru_layer<<<256, 512, 0, stream>>>(wHb0, wHb1, Whh_l, bhh_l, wGx, yb, yf, h0_l, wBar);
  }
}

// Round 8
// 10883.912 us; speedup vs baseline: 1.2531x; 1.2531x over previous
//
#include <hip/hip_runtime.h>
#include <stdint.h>

typedef uint16_t u16;
typedef __attribute__((ext_vector_type(8))) short bf16x8;   // 8 bf16 in 4 VGPRs
typedef __attribute__((ext_vector_type(4))) float f32x4;

#define DEVI __device__ __forceinline__

DEVI u16 f2b(float f) {                       // f32 -> bf16 RNE
  uint32_t u = __float_as_uint(f);
  uint32_t r = (u + 0x7fffu + ((u >> 16) & 1u)) >> 16;
  return (u16)r;
}
DEVI float b2f(u16 h) { return __uint_as_float(((uint32_t)h) << 16); }

typedef const __attribute__((address_space(1))) uint32_t* gptr_t;
typedef __attribute__((address_space(3))) uint32_t* lptr_t;
DEVI void gload_lds16(const void* g, void* l) {
  __builtin_amdgcn_global_load_lds((gptr_t)g, (lptr_t)l, 16, 0, 0);
}

// L2-bypass (coherent-at-L3) accessors for cross-XCD h exchange. PROVEN (R3/R4).
DEVI bf16x8 ld_cc16(const u16* p) {
  bf16x8 r;
  asm volatile("global_load_dwordx4 %0, %1, off sc0 sc1" : "=v"(r) : "v"(p));
  return r;   // caller must s_waitcnt vmcnt(0) + sched_barrier before use
}
DEVI void st_cc2(u16* p, u16 v) {
  uint32_t d = v;
  asm volatile("global_store_short %0, %1, off sc0 sc1" :: "v"(p), "v"(d) : "memory");
}

// ---------------------------------------------------------------- converts
__global__ void cvt_f32_bf16(const float* __restrict__ in, u16* __restrict__ out, long n) {
  long i = ((long)blockIdx.x * blockDim.x + threadIdx.x) * 4;
  long stride = (long)gridDim.x * blockDim.x * 4;
  for (; i < n; i += stride) {
    float4 v = *(const float4*)(in + i);
    ushort4 o;
    o.x = f2b(v.x); o.y = f2b(v.y); o.z = f2b(v.z); o.w = f2b(v.w);
    *(ushort4*)(out + i) = o;
  }
}

// ---------------------------------------------------------------- GEMM (unchanged)
__global__ __launch_bounds__(256) void gemm_bt_bias(
    const u16* __restrict__ A, const u16* __restrict__ W,
    const float* __restrict__ bias, u16* __restrict__ C, int K) {
  constexpr int NLD = 6144;
  __shared__ u16 As[128 * 64];
  __shared__ u16 Bs[128 * 64];
  const int t = threadIdx.x;
  const int l = t & 63, w = t >> 6;
  const int lr = l & 15, lk = l >> 4;
  const long bm = (long)blockIdx.y * 128;
  const long bn = (long)blockIdx.x * 128;
  const int wm = (w >> 1) * 64, wn = (w & 1) * 64;

  f32x4 acc[4][4] = {};

  for (int k0 = 0; k0 < K; k0 += 64) {
    __syncthreads();
    #pragma unroll
    for (int i = 0; i < 4; ++i) {
      int slot = i * 256 + t;
      int row = slot >> 3, s = slot & 7;
      int c8 = (s ^ (row & 7)) * 8;
      char* la = (char*)As + (size_t)(i * 256 + w * 64) * 16;
      char* lb = (char*)Bs + (size_t)(i * 256 + w * 64) * 16;
      gload_lds16(A + (bm + row) * K + k0 + c8, la);
      gload_lds16(W + (bn + row) * K + k0 + c8, lb);
    }
    asm volatile("s_waitcnt vmcnt(0)" ::: "memory");
    __syncthreads();
    #pragma unroll
    for (int kk = 0; kk < 2; ++kk) {
      bf16x8 af[4], bfr[4];
      #pragma unroll
      for (int mi = 0; mi < 4; ++mi) {
        int row = wm + mi * 16 + lr;
        int sl = (kk * 4 + lk) ^ (row & 7);
        af[mi] = *(const bf16x8*)((const char*)As + row * 128 + sl * 16);
      }
      #pragma unroll
      for (int ni = 0; ni < 4; ++ni) {
        int row = wn + ni * 16 + lr;
        int sl = (kk * 4 + lk) ^ (row & 7);
        bfr[ni] = *(const bf16x8*)((const char*)Bs + row * 128 + sl * 16);
      }
      #pragma unroll
      for (int mi = 0; mi < 4; ++mi)
        #pragma unroll
        for (int ni = 0; ni < 4; ++ni)
          acc[mi][ni] = __builtin_amdgcn_mfma_f32_16x16x32_bf16(af[mi], bfr[ni], acc[mi][ni], 0, 0, 0);
    }
  }

  float bv[4];
  #pragma unroll
  for (int ni = 0; ni < 4; ++ni) bv[ni] = bias[bn + wn + ni * 16 + lr];
  #pragma unroll
  for (int mi = 0; mi < 4; ++mi)
    #pragma unroll
    for (int ni = 0; ni < 4; ++ni) {
      long col = bn + wn + ni * 16 + lr;
      #pragma unroll
      for (int j = 0; j < 4; ++j) {
        long row = bm + wm + mi * 16 + lk * 4 + j;
        C[row * NLD + col] = f2b(acc[mi][ni][j] + bv[ni]);
      }
    }
}

// ---------------------------------------------------------------- flat barrier (PROVEN R3/R4)
// Domain = (dir, rp): 64 WGs. 8 leaf counters (spaced 256B), 8 arrivals each,
// monotone (no resets). Arrive at own leaf, poll all 8. Relaxed-only atomics;
// data visibility via sc0/sc1 h accesses.
DEVI void poll8(unsigned* leaves, unsigned tgt) {
  for (;;) {
    unsigned ok = 1u;
    #pragma unroll
    for (int i = 0; i < 8; ++i)
      ok &= (unsigned)(__hip_atomic_load(&leaves[i * 64], __ATOMIC_RELAXED, __HIP_MEMORY_SCOPE_AGENT) >= tgt);
    if (ok) break;
    __builtin_amdgcn_s_sleep(1);
  }
}

// ---------------------------------------------------------------- persistent GRU layer
// grid = 256 WGs x 512 thr (8 waves), 1 WG/CU. WG = (dir, jg, rp). Wave w2:
// kh=w2&3 (K-quarter), rt2=w2>>2 (16-row group). Weights parked in 96 AGPRs:
// "+a" launder makes them un-rematerializable (loads provably hoisted out of
// the t-loop); consumed by BUILTIN MFMA (compiler scheduling, no s_nops).
// f32 master h in finish-lane regs; bf16 h published via sc0/sc1 (L3-coherent).
__global__ __launch_bounds__(512, 2) void gru_layer(
    u16* __restrict__ hbA, u16* __restrict__ hbB,
    const u16* __restrict__ Whh,   // [2,3072,1024] bf16 (this layer)
    const float* __restrict__ bhh, // [2,3072] f32
    const u16* __restrict__ gx,    // [32768,6144] bf16
    u16* __restrict__ y_b, float* __restrict__ y_f,   // one non-null
    const float* __restrict__ h0l, // [2,64,1024] f32 (this layer)
    unsigned* bar) {
  __shared__ float lds[8 * 64 * 13];

  const int bid = blockIdx.x;
  const int dir = bid >> 7;
  const int v = bid & 127;
  const int jg = v >> 1, rp = v & 1;
  const int tid = threadIdx.x;
  const int w2 = tid >> 6, l = tid & 63;
  const int lr = l & 15, lk = l >> 4;
  const int kh = w2 & 3, rt2 = w2 >> 2;
  const int rowbase = rp * 32 + rt2 * 16;

  unsigned* leaves = bar + (size_t)(dir * 2 + rp) * 512;   // leaf i at +i*64
  const int sub = jg & 7;

  // ---- resident weights: laundered pointer + AGPR-parked values
  const u16* wb = Whh + ((size_t)dir * 3072 + jg * 16 + lr) * 1024 + kh * 256 + lk * 8;
  asm volatile("" : "+v"(wb));
  bf16x8 wr[8], wz[8], wn[8];
  #pragma unroll
  for (int kk = 0; kk < 8; ++kk) {
    wr[kk] = *(const bf16x8*)(wb + kk * 32);
    wz[kk] = *(const bf16x8*)(wb + 1024 * 1024 + kk * 32);
    wn[kk] = *(const bf16x8*)(wb + 2048 * 1024 + kk * 32);
  }
  #pragma unroll
  for (int kk = 0; kk < 8; ++kk)
    asm volatile("" : "+a"(wr[kk]), "+a"(wz[kk]), "+a"(wn[kk]));

  // ---- finish-lane constants + h-state init
  const int rl = tid >> 4, cl = tid & 15;     // rl in [0,32), cl in [0,16)
  const int fcol = jg * 16 + cl;
  const int frow = rp * 32 + rl;
  const float bhr = bhh[dir * 3072 + fcol];
  const float bhz = bhh[dir * 3072 + 1024 + fcol];
  const float bhn = bhh[dir * 3072 + 2048 + fcol];
  const size_t hoff = (size_t)(dir * 64 + frow) * 1024 + fcol;
  float hp = h0l[hoff];
  st_cc2(hbA + hoff, f2b(hp));                // visible at L3 to all XCDs

  const int tt0 = dir ? 511 : 0;
  long gxp = (long)(tt0 * 64 + frow) * 6144 + (long)dir * 3072 + fcol;
  const long gxstep = dir ? -(64 * 6144) : (64 * 6144);
  long yp = (long)(tt0 * 64 + frow) * 2048 + (long)dir * 1024 + fcol;
  const long ystep = dir ? -(64 * 2048) : (64 * 2048);

  const u16* apA = hbA + (size_t)(dir * 64 + rowbase + lr) * 1024 + kh * 256 + lk * 8;
  const u16* apB = hbB + (size_t)(dir * 64 + rowbase + lr) * 1024 + kh * 256 + lk * 8;

  const int rt2f = rl >> 4, r16 = rl & 15, jj = r16 & 3;
  const int lane2 = (r16 >> 2) * 16 + cl;

  // gx prefetch for t=0
  u16 gcr = gx[gxp], gcz = gx[gxp + 1024], gcn = gx[gxp + 2048];

  asm volatile("s_waitcnt vmcnt(0)" ::: "memory");   // init store drained to L3
  __syncthreads();
  if (tid == 0) {
    __hip_atomic_fetch_add(&leaves[sub * 64], 1u, __ATOMIC_RELAXED, __HIP_MEMORY_SCOPE_AGENT);
    poll8(leaves, 8u);
  }
  __syncthreads();

  for (int t = 0; t < 512; ++t) {
    // ---- compute: partial gh over this wave's K-quarter (24 MFMAs)
    const u16* ap = (t & 1) ? apB : apA;
    u16* hb_out = (t & 1) ? hbA : hbB;
    bf16x8 av[8];
    #pragma unroll
    for (int kk = 0; kk < 8; ++kk) av[kk] = ld_cc16(ap + kk * 32);
    asm volatile("s_waitcnt vmcnt(0)" ::: "memory");
    __builtin_amdgcn_sched_barrier(0);

    f32x4 aR = {0.f, 0.f, 0.f, 0.f}, aZ = {0.f, 0.f, 0.f, 0.f}, aN = {0.f, 0.f, 0.f, 0.f};
    #pragma unroll
    for (int kk = 0; kk < 8; ++kk) {
      aR = __builtin_amdgcn_mfma_f32_16x16x32_bf16(av[kk], wr[kk], aR, 0, 0, 0);
      aZ = __builtin_amdgcn_mfma_f32_16x16x32_bf16(av[kk], wz[kk], aZ, 0, 0, 0);
      aN = __builtin_amdgcn_mfma_f32_16x16x32_bf16(av[kk], wn[kk], aN, 0, 0, 0);
    }
    float* myl = lds + (size_t)(w2 * 64 + l) * 13;
    #pragma unroll
    for (int j = 0; j < 4; ++j) { myl[j] = aR[j]; myl[4 + j] = aZ[j]; myl[8 + j] = aN[j]; }
    __syncthreads();

    // ---- finish: combine 4 K-partials, prefetch next gx, gate math
    float ghr = 0.f, ghz = 0.f, ghn = 0.f;
    #pragma unroll
    for (int k2 = 0; k2 < 4; ++k2) {
      const float* pl = lds + (size_t)((rt2f * 4 + k2) * 64 + lane2) * 13;
      ghr += pl[jj]; ghz += pl[4 + jj]; ghn += pl[8 + jj];
    }
    long gxn_p = gxp + gxstep;                 // t=511 prefetch lands in ws padding (unused)
    u16 g2r = gx[gxn_p], g2z = gx[gxn_p + 1024], g2n = gx[gxn_p + 2048];

    float rg = 1.f / (1.f + __expf(-(b2f(gcr) + ghr + bhr)));
    float zg = 1.f / (1.f + __expf(-(b2f(gcz) + ghz + bhz)));
    float ng = tanhf(b2f(gcn) + rg * (ghn + bhn));
    hp = (1.f - zg) * ng + zg * hp;
    st_cc2(hb_out + hoff, f2b(hp));
    if (y_b) y_b[yp] = f2b(hp);
    else     y_f[yp] = hp;

    asm volatile("s_waitcnt vmcnt(0)" ::: "memory");   // h at L3; g2* arrived
    gcr = g2r; gcz = g2z; gcn = g2n; gxp = gxn_p; yp += ystep;

    __syncthreads();
    if (tid == 0) {
      __hip_atomic_fetch_add(&leaves[sub * 64], 1u, __ATOMIC_RELAXED, __HIP_MEMORY_SCOPE_AGENT);
      poll8(leaves, (unsigned)(8 * (t + 2)));
    }
    __syncthreads();
  }
}

// ---------------------------------------------------------------- launch
extern "C" void kernel_launch(void* const* d_in, const int* in_sizes, int n_in,
                              void* d_out, int out_size, void* d_ws, size_t ws_size,
                              hipStream_t stream) {
  (void)in_sizes; (void)n_in; (void)out_size; (void)ws_size;
  const float* x     = (const float*)d_in[0];   // [512,64,1024]
  const float* h0    = (const float*)d_in[1];   // [6,64,1024]
  const float* w_ih0 = (const float*)d_in[2];   // [2,3072,1024]
  const float* w_ih  = (const float*)d_in[3];   // [2,2,3072,2048]
  const float* w_hh  = (const float*)d_in[4];   // [3,2,3072,1024]
  const float* b_ih  = (const float*)d_in[5];   // [3,2,3072]
  const float* b_hh  = (const float*)d_in[6];   // [3,2,3072]
  float* out = (float*)d_out;                   // [512,64,2048]

  char* p = (char*)d_ws;
  u16* wA    = (u16*)p; p += (size_t)32768 * 2048 * 2;       // layer input bf16
  u16* wGx   = (u16*)p; p += (size_t)32768 * 6144 * 2;       // gate preacts bf16
  u16* wWih0 = (u16*)p; p += (size_t)6144 * 1024 * 2;
  u16* wWih  = (u16*)p; p += (size_t)2 * 6144 * 2048 * 2;
  u16* wWhh  = (u16*)p; p += (size_t)6 * 3072 * 1024 * 2;
  u16* wHb0  = (u16*)p; p += (size_t)2 * 64 * 1024 * 2;
  u16* wHb1  = (u16*)p; p += (size_t)2 * 64 * 1024 * 2;
  unsigned* wBar = (unsigned*)p; p += 4096 * 4;

  cvt_f32_bf16<<<2048, 256, 0, stream>>>(x,     wA,    (long)33554432);
  cvt_f32_bf16<<<2048, 256, 0, stream>>>(w_ih0, wWih0, (long)6291456);
  cvt_f32_bf16<<<2048, 256, 0, stream>>>(w_ih,  wWih,  (long)25165824);
  cvt_f32_bf16<<<2048, 256, 0, stream>>>(w_hh,  wWhh,  (long)18874368);

  for (int layer = 0; layer < 3; ++layer) {
    int K = (layer == 0) ? 1024 : 2048;
    const u16* Wg = (layer == 0) ? wWih0 : (wWih + (size_t)(layer - 1) * 6144 * 2048);
    gemm_bt_bias<<<dim3(48, 256), 256, 0, stream>>>(wA, Wg, b_ih + (size_t)layer * 6144, wGx, K);

    hipMemsetAsync(wBar, 0, 4096 * 4, stream);

    const u16* Whh_l   = wWhh + (size_t)layer * 2 * 3072 * 1024;
    const float* bhh_l = b_hh + (size_t)layer * 6144;
    const float* h0_l  = h0 + (size_t)layer * 131072;
    u16*   yb = (layer < 2) ? wA : nullptr;
    float* yf = (layer < 2) ? nullptr : out;
    gru_layer<<<256, 512, 0, stream>>>(wHb0, wHb1, Whh_l, bhh_l, wGx, yb, yf, h0_l, wBar);
  }
}

// Round 9
// 9075.378 us; speedup vs baseline: 1.5028x; 1.1993x over previous
//
#include <hip/hip_runtime.h>
#include <stdint.h>

typedef uint16_t u16;
typedef __attribute__((ext_vector_type(8))) short bf16x8;   // 8 bf16 in 4 VGPRs
typedef __attribute__((ext_vector_type(4))) float f32x4;
typedef __attribute__((ext_vector_type(4))) unsigned u32x4;

#define DEVI __device__ __forceinline__

DEVI u16 f2b(float f) {                       // f32 -> bf16 RNE
  uint32_t u = __float_as_uint(f);
  uint32_t r = (u + 0x7fffu + ((u >> 16) & 1u)) >> 16;
  return (u16)r;
}
DEVI float b2f(u16 h) { return __uint_as_float(((uint32_t)h) << 16); }

typedef const __attribute__((address_space(1))) uint32_t* gptr_t;
typedef __attribute__((address_space(3))) uint32_t* lptr_t;
DEVI void gload_lds16(const void* g, void* l) {
  __builtin_amdgcn_global_load_lds((gptr_t)g, (lptr_t)l, 16, 0, 0);
}

// L2-bypass (coherent-at-L3) accessors for cross-XCD exchange. PROVEN (R3/R4/R8).
DEVI bf16x8 ld_cc16(const u16* p) {
  bf16x8 r;
  asm volatile("global_load_dwordx4 %0, %1, off sc0 sc1" : "=v"(r) : "v"(p));
  return r;   // caller must s_waitcnt vmcnt(0) + sched_barrier before use
}
DEVI void st_cc2(u16* p, u16 v) {
  uint32_t d = v;
  asm volatile("global_store_short %0, %1, off sc0 sc1" :: "v"(p), "v"(d) : "memory");
}
DEVI void st_cc4(unsigned* p, unsigned v) {
  asm volatile("global_store_dword %0, %1, off sc0 sc1" :: "v"(p), "v"(v) : "memory");
}

// ---------------------------------------------------------------- converts
__global__ void cvt_f32_bf16(const float* __restrict__ in, u16* __restrict__ out, long n) {
  long i = ((long)blockIdx.x * blockDim.x + threadIdx.x) * 4;
  long stride = (long)gridDim.x * blockDim.x * 4;
  for (; i < n; i += stride) {
    float4 v = *(const float4*)(in + i);
    ushort4 o;
    o.x = f2b(v.x); o.y = f2b(v.y); o.z = f2b(v.z); o.w = f2b(v.w);
    *(ushort4*)(out + i) = o;
  }
}

// ---------------------------------------------------------------- GEMM (unchanged)
__global__ __launch_bounds__(256) void gemm_bt_bias(
    const u16* __restrict__ A, const u16* __restrict__ W,
    const float* __restrict__ bias, u16* __restrict__ C, int K) {
  constexpr int NLD = 6144;
  __shared__ u16 As[128 * 64];
  __shared__ u16 Bs[128 * 64];
  const int t = threadIdx.x;
  const int l = t & 63, w = t >> 6;
  const int lr = l & 15, lk = l >> 4;
  const long bm = (long)blockIdx.y * 128;
  const long bn = (long)blockIdx.x * 128;
  const int wm = (w >> 1) * 64, wn = (w & 1) * 64;

  f32x4 acc[4][4] = {};

  for (int k0 = 0; k0 < K; k0 += 64) {
    __syncthreads();
    #pragma unroll
    for (int i = 0; i < 4; ++i) {
      int slot = i * 256 + t;
      int row = slot >> 3, s = slot & 7;
      int c8 = (s ^ (row & 7)) * 8;
      char* la = (char*)As + (size_t)(i * 256 + w * 64) * 16;
      char* lb = (char*)Bs + (size_t)(i * 256 + w * 64) * 16;
      gload_lds16(A + (bm + row) * K + k0 + c8, la);
      gload_lds16(W + (bn + row) * K + k0 + c8, lb);
    }
    asm volatile("s_waitcnt vmcnt(0)" ::: "memory");
    __syncthreads();
    #pragma unroll
    for (int kk = 0; kk < 2; ++kk) {
      bf16x8 af[4], bfr[4];
      #pragma unroll
      for (int mi = 0; mi < 4; ++mi) {
        int row = wm + mi * 16 + lr;
        int sl = (kk * 4 + lk) ^ (row & 7);
        af[mi] = *(const bf16x8*)((const char*)As + row * 128 + sl * 16);
      }
      #pragma unroll
      for (int ni = 0; ni < 4; ++ni) {
        int row = wn + ni * 16 + lr;
        int sl = (kk * 4 + lk) ^ (row & 7);
        bfr[ni] = *(const bf16x8*)((const char*)Bs + row * 128 + sl * 16);
      }
      #pragma unroll
      for (int mi = 0; mi < 4; ++mi)
        #pragma unroll
        for (int ni = 0; ni < 4; ++ni)
          acc[mi][ni] = __builtin_amdgcn_mfma_f32_16x16x32_bf16(af[mi], bfr[ni], acc[mi][ni], 0, 0, 0);
    }
  }

  float bv[4];
  #pragma unroll
  for (int ni = 0; ni < 4; ++ni) bv[ni] = bias[bn + wn + ni * 16 + lr];
  #pragma unroll
  for (int mi = 0; mi < 4; ++mi)
    #pragma unroll
    for (int ni = 0; ni < 4; ++ni) {
      long col = bn + wn + ni * 16 + lr;
      #pragma unroll
      for (int j = 0; j < 4; ++j) {
        long row = bm + wm + mi * 16 + lk * 4 + j;
        C[row * NLD + col] = f2b(acc[mi][ni][j] + bv[ni]);
      }
    }
}

// ---------------------------------------------------------------- slot barrier
// Store-only (no RMW): WG tid0 stores its monotone stamp (sc0sc1 -> L3).
// ALL waves poll the domain's 32 slots (8 lanes x dwordx4) until >= target.
// Safety: stamps are monotone; own-WG stamp implies own syncthreads passed.
DEVI void poll_slots(const unsigned* slots, unsigned tgt, int l) {
  const unsigned* pp = slots + (l & 7) * 4;
  for (;;) {
    u32x4 v;
    asm volatile("global_load_dwordx4 %0, %1, off sc0 sc1" : "=v"(v) : "v"(pp));
    asm volatile("s_waitcnt vmcnt(0)" ::: "memory");
    int ok = (l < 8) ? (v.x >= tgt && v.y >= tgt && v.z >= tgt && v.w >= tgt) : 1;
    if (__all(ok)) break;
    __builtin_amdgcn_s_sleep(1);
  }
}

// ---------------------------------------------------------------- persistent GRU layer
// 256 WGs x 512 thr (8 waves, 1 WG/CU). WG: domain dmn=bid&7 (dir=dmn>>2,
// rowgroup rg=dmn&3 -> 16 batch rows), col-tile m=bid>>3 (32 cols). Domain =
// 32 WGs exchanging h via sc0sc1 (L3-coherent, PROVEN). Store-only slot
// barrier, all-wave polling. Weights parked in 96 AGPRs, builtin MFMA.
__global__ __launch_bounds__(512, 2) void gru_layer(
    u16* __restrict__ hbA, u16* __restrict__ hbB,
    const u16* __restrict__ Whh,   // [2,3072,1024] bf16 (this layer)
    const float* __restrict__ bhh, // [2,3072] f32
    const u16* __restrict__ gx,    // [32768,6144] bf16
    u16* __restrict__ y_b, float* __restrict__ y_f,   // one non-null
    const float* __restrict__ h0l, // [2,64,1024] f32 (this layer)
    unsigned* bar) {
  __shared__ float lds[8 * 64 * 13];

  const int bid = blockIdx.x;
  const int dmn = bid & 7, m = bid >> 3;
  const int dir = dmn >> 2, rg = dmn & 3;
  const int tid = threadIdx.x;
  const int w2 = tid >> 6, l = tid & 63;
  const int lr = l & 15, lk = l >> 4;
  const int ch = w2 & 1, kh = w2 >> 1;

  unsigned* slots = bar + dmn * 64;           // 32 stamps per domain, 256B apart

  // ---- finish-lane constants + h0 init
  const int fcol5 = tid & 31, frow = tid >> 5;      // 32 cols x 16 rows
  const int colg = m * 32 + fcol5;
  const int growd = rg * 16 + frow;
  const float bhr = bhh[dir * 3072 + colg];
  const float bhz = bhh[dir * 3072 + 1024 + colg];
  const float bhn = bhh[dir * 3072 + 2048 + colg];
  const size_t hoff = (size_t)(dir * 64 + growd) * 1024 + colg;
  float hp = h0l[hoff];
  st_cc2(hbA + hoff, f2b(hp));                // visible at L3 to all XCDs

  // ---- weights -> AGPRs (3 gates x 16 cols x 256 K per wave = 96 AGPRs)
  const u16* wb = Whh + ((size_t)(dir * 3072 + m * 32 + ch * 16 + lr)) * 1024 + kh * 256 + lk * 8;
  asm volatile("" : "+v"(wb));
  bf16x8 wr[8], wz[8], wn[8];
  #pragma unroll
  for (int kk = 0; kk < 8; ++kk) {
    wr[kk] = *(const bf16x8*)(wb + kk * 32);
    wz[kk] = *(const bf16x8*)(wb + 1024 * 1024 + kk * 32);
    wn[kk] = *(const bf16x8*)(wb + 2048 * 1024 + kk * 32);
  }
  #pragma unroll
  for (int kk = 0; kk < 8; ++kk)
    asm volatile("" : "+a"(wr[kk]), "+a"(wz[kk]), "+a"(wn[kk]));

  // ---- loop state
  const int tt0 = dir ? 511 : 0;
  long gxp = (long)(tt0 * 64 + growd) * 6144 + (long)dir * 3072 + colg;
  const long gxstep = dir ? -(64 * 6144) : (64 * 6144);
  long yp = (long)(tt0 * 64 + growd) * 2048 + (long)dir * 1024 + colg;
  const long ystep = dir ? -(64 * 2048) : (64 * 2048);

  const u16* apA = hbA + (size_t)(dir * 64 + rg * 16 + lr) * 1024 + kh * 256 + lk * 8;
  const u16* apB = hbB + (size_t)(dir * 64 + rg * 16 + lr) * 1024 + kh * 256 + lk * 8;

  const int lf = ((frow >> 2) << 4) | (fcol5 & 15);  // source lane in compute wave
  const int jj = frow & 3;                           // acc reg index
  const int chf = fcol5 >> 4;                        // source col-half

  // gx prefetch for t=0 (plain cached)
  u16 gcr = gx[gxp], gcz = gx[gxp + 1024], gcn = gx[gxp + 2048];

  asm volatile("s_waitcnt vmcnt(0)" ::: "memory");   // h0 publish drained to L3
  __syncthreads();
  if (tid == 0) st_cc4(slots + m, 1u);
  poll_slots(slots, 1u, l);

  for (int t = 0; t < 512; ++t) {
    const u16* ap = (t & 1) ? apB : apA;
    u16* hb_out = (t & 1) ? hbA : hbB;

    // ---- h loads for this wave's K-quarter (8 x dwordx4, sc0sc1)
    bf16x8 av[8];
    #pragma unroll
    for (int kk = 0; kk < 8; ++kk) av[kk] = ld_cc16(ap + kk * 32);
    asm volatile("s_waitcnt vmcnt(0)" ::: "memory");
    __builtin_amdgcn_sched_barrier(0);

    // ---- 24 MFMAs: 3 gate chains over this wave's K-quarter
    f32x4 aR = {0.f,0.f,0.f,0.f}, aZ = {0.f,0.f,0.f,0.f}, aN = {0.f,0.f,0.f,0.f};
    #pragma unroll
    for (int kk = 0; kk < 8; ++kk) {
      aR = __builtin_amdgcn_mfma_f32_16x16x32_bf16(av[kk], wr[kk], aR, 0, 0, 0);
      aZ = __builtin_amdgcn_mfma_f32_16x16x32_bf16(av[kk], wz[kk], aZ, 0, 0, 0);
      aN = __builtin_amdgcn_mfma_f32_16x16x32_bf16(av[kk], wn[kk], aN, 0, 0, 0);
    }
    float* myl = lds + (size_t)(w2 * 64 + l) * 13;
    #pragma unroll
    for (int j = 0; j < 4; ++j) { myl[j] = aR[j]; myl[4 + j] = aZ[j]; myl[8 + j] = aN[j]; }
    __syncthreads();

    // ---- finish: combine 4 K-quarter partials, prefetch next gx, gate math
    float ghr = 0.f, ghz = 0.f, ghn = 0.f;
    #pragma unroll
    for (int k2 = 0; k2 < 4; ++k2) {
      const float* pl = lds + (size_t)((k2 * 2 + chf) * 64 + lf) * 13;
      ghr += pl[jj]; ghz += pl[4 + jj]; ghn += pl[8 + jj];
    }
    long gxn_p = gxp + gxstep;                 // t=511 prefetch strays inside ws (harmless)
    u16 g2r = gx[gxn_p], g2z = gx[gxn_p + 1024], g2n = gx[gxn_p + 2048];

    float rgt = 1.f / (1.f + __expf(-(b2f(gcr) + ghr + bhr)));
    float zgt = 1.f / (1.f + __expf(-(b2f(gcz) + ghz + bhz)));
    float ngt = tanhf(b2f(gcn) + rgt * (ghn + bhn));
    hp = (1.f - zgt) * ngt + zgt * hp;
    st_cc2(hb_out + hoff, f2b(hp));
    if (y_b) y_b[yp] = f2b(hp);
    else     y_f[yp] = hp;

    asm volatile("s_waitcnt vmcnt(0)" ::: "memory");  // publish + y + g2 drained
    gcr = g2r; gcz = g2z; gcn = g2n; gxp = gxn_p; yp += ystep;

    __syncthreads();                                   // all waves drained
    if (tid == 0) st_cc4(slots + m, (unsigned)(t + 2));
    poll_slots(slots, (unsigned)(t + 2), l);           // all waves self-release
  }
}

// ---------------------------------------------------------------- launch
extern "C" void kernel_launch(void* const* d_in, const int* in_sizes, int n_in,
                              void* d_out, int out_size, void* d_ws, size_t ws_size,
                              hipStream_t stream) {
  (void)in_sizes; (void)n_in; (void)out_size; (void)ws_size;
  const float* x     = (const float*)d_in[0];   // [512,64,1024]
  const float* h0    = (const float*)d_in[1];   // [6,64,1024]
  const float* w_ih0 = (const float*)d_in[2];   // [2,3072,1024]
  const float* w_ih  = (const float*)d_in[3];   // [2,2,3072,2048]
  const float* w_hh  = (const float*)d_in[4];   // [3,2,3072,1024]
  const float* b_ih  = (const float*)d_in[5];   // [3,2,3072]
  const float* b_hh  = (const float*)d_in[6];   // [3,2,3072]
  float* out = (float*)d_out;                   // [512,64,2048]

  char* p = (char*)d_ws;
  u16* wA    = (u16*)p; p += (size_t)32768 * 2048 * 2;       // layer input bf16
  u16* wGx   = (u16*)p; p += (size_t)32768 * 6144 * 2;       // gate preacts bf16
  u16* wWih0 = (u16*)p; p += (size_t)6144 * 1024 * 2;
  u16* wWih  = (u16*)p; p += (size_t)2 * 6144 * 2048 * 2;
  u16* wWhh  = (u16*)p; p += (size_t)6 * 3072 * 1024 * 2;
  u16* wHb0  = (u16*)p; p += (size_t)2 * 64 * 1024 * 2;
  u16* wHb1  = (u16*)p; p += (size_t)2 * 64 * 1024 * 2;
  unsigned* wBar = (unsigned*)p; p += 4096 * 4;

  cvt_f32_bf16<<<2048, 256, 0, stream>>>(x,     wA,    (long)33554432);
  cvt_f32_bf16<<<2048, 256, 0, stream>>>(w_ih0, wWih0, (long)6291456);
  cvt_f32_bf16<<<2048, 256, 0, stream>>>(w_ih,  wWih,  (long)25165824);
  cvt_f32_bf16<<<2048, 256, 0, stream>>>(w_hh,  wWhh,  (long)18874368);

  for (int layer = 0; layer < 3; ++layer) {
    int K = (layer == 0) ? 1024 : 2048;
    const u16* Wg = (layer == 0) ? wWih0 : (wWih + (size_t)(layer - 1) * 6144 * 2048);
    gemm_bt_bias<<<dim3(48, 256), 256, 0, stream>>>(wA, Wg, b_ih + (size_t)layer * 6144, wGx, K);

    hipMemsetAsync(wBar, 0, 4096 * 4, stream);

    const u16* Whh_l   = wWhh + (size_t)layer * 2 * 3072 * 1024;
    const float* bhh_l = b_hh + (size_t)layer * 6144;
    const float* h0_l  = h0 + (size_t)layer * 131072;
    u16*   yb = (layer < 2) ? wA : nullptr;
    float* yf = (layer < 2) ? nullptr : out;
    gru_layer<<<256, 512, 0, stream>>>(wHb0, wHb1, Whh_l, bhh_l, wGx, yb, yf, h0_l, wBar);
  }
}